// Round 3
// baseline (59.663 us; speedup 1.0000x reference)
//
#include <hip/hip_runtime.h>
#include <stdint.h>
#include <math.h>

// Problem geometry (fixed by reference)
#define HWPIX 65536         // 256*256
#define NCH   18
#define NHYP  1024
#define NK    9
#define NBK   72            // B*K = 8*9
#define INV_LOG2 1.4426950408889634f
#define TINYF 1.1754943508222875e-38f

#define NVBLK 2048          // pixel (vote) kernel blocks
#define VITER 9             // (2*8*18*16384) / (2048*256) grid-stride iterations
#define NSBLK 512           // seg kernel blocks
// ws layout (floats)
#define OFS_VOTE 64                         // [2][NVBLK]
#define OFS_CNT  (OFS_VOTE + 2 * NVBLK)     // [2][NSBLK]
#define OFS_SEG  (OFS_CNT  + 2 * NSBLK)     // [2][NSBLK]
#define OFS_KP   (OFS_SEG  + 2 * NSBLK)     // [2][NBK]
#define OFS_ENT  (OFS_KP   + 2 * NBK)       // [2][NBK]
#define OFS_Y    (OFS_ENT  + 2 * NBK)       // [2][NBK]

// ---- Threefry-2x32, 20 rounds (JAX-compatible) ----
__host__ __device__ inline void tf2x32(uint32_t k0, uint32_t k1,
                                       uint32_t x0, uint32_t x1,
                                       uint32_t& o0, uint32_t& o1) {
  uint32_t ks2 = k0 ^ k1 ^ 0x1BD11BDAu;
  x0 += k0; x1 += k1;
#define TFR(r) { x0 += x1; x1 = (x1 << (r)) | (x1 >> (32 - (r))); x1 ^= x0; }
  TFR(13) TFR(15) TFR(26) TFR(6)   x0 += k1;  x1 += ks2 + 1u;
  TFR(17) TFR(29) TFR(16) TFR(24)  x0 += ks2; x1 += k0 + 2u;
  TFR(13) TFR(15) TFR(26) TFR(6)   x0 += k0;  x1 += k1 + 3u;
  TFR(17) TFR(29) TFR(16) TFR(24)  x0 += k1;  x1 += ks2 + 4u;
  TFR(13) TFR(15) TFR(26) TFR(6)   x0 += ks2; x1 += k0 + 5u;
#undef TFR
  o0 = x0; o1 = x1;
}

__device__ inline float blk_sum(float v, float* sm) {
  int t = threadIdx.x;
  sm[t] = v; __syncthreads();
  for (int off = 128; off > 0; off >>= 1) {
    if (t < off) sm[t] += sm[t + off];
    __syncthreads();
  }
  float r = sm[0]; __syncthreads();
  return r;
}

__device__ inline float sl1(float x, float y, float w) {
  const float dd = fabsf(x - y) * w;
  return (dd < 1.f) ? 0.5f * dd * dd : dd - 0.5f;
}

__device__ inline float nll2(float s0, float s1, int lbl) {
  const float mx = fmaxf(s0, s1);
  const float mn = fminf(s0, s1);
  const float l = mx + logf(1.0f + expf(mn - mx));
  return l - (lbl ? s1 : s0);
}

// ---- Kernel 1: masked smooth-L1 vote sum, contiguous streaming ----
// Flat quad space: Fq over [side(2)][b(8)][c(18)][hwq(16384)]; plane = Fq>>14.
// 2048 blocks x 256 thr, 9 grid-stride iters in 3 batches of 3; loads batched
// ahead of compute with a sched fence to force 9 loads in flight.
__global__ __launch_bounds__(256) void pixel_kernel(
    const float* __restrict__ vpL, const float* __restrict__ vgL,
    const int*   __restrict__ mkL,
    const float* __restrict__ vpR, const float* __restrict__ vgR,
    const int*   __restrict__ mkR,
    float* __restrict__ ws) {
  const int tid = blockIdx.x * 256 + threadIdx.x;   // 0..524287
  float vL = 0.f, vR = 0.f;

#pragma unroll
  for (int batch = 0; batch < 3; ++batch) {
    int4 m4[3]; float4 p4[3], q4[3]; int sd[3];
#pragma unroll
    for (int j = 0; j < 3; ++j) {
      const int Fq    = tid + (batch * 3 + j) * (NVBLK * 256);
      const int plane = Fq >> 14;               // 0..287
      const int hwq   = Fq & 16383;
      const int side  = plane >= 144;
      const int lp    = plane - side * 144;     // b*18 + c
      const int b     = lp / 18;
      const float* vp = side ? vpR : vpL;
      const float* vg = side ? vgR : vgL;
      const int*   mk = side ? mkR : mkL;
      const size_t voff = ((size_t)lp << 16) + ((size_t)hwq << 2);
      m4[j] = *(const int4*)(mk + ((size_t)b << 16) + ((size_t)hwq << 2));
      p4[j] = *(const float4*)(vp + voff);
      q4[j] = *(const float4*)(vg + voff);
      sd[j] = side;
    }
    __builtin_amdgcn_sched_barrier(0);   // keep the 9 loads clustered
#pragma unroll
    for (int j = 0; j < 3; ++j) {
      float v = 0.f;
      v += sl1(p4[j].x, q4[j].x, (float)m4[j].x);
      v += sl1(p4[j].y, q4[j].y, (float)m4[j].y);
      v += sl1(p4[j].z, q4[j].z, (float)m4[j].z);
      v += sl1(p4[j].w, q4[j].w, (float)m4[j].w);
      vL += sd[j] ? 0.f : v;
      vR += sd[j] ? v : 0.f;
    }
  }

  __shared__ float sm[256];
  const float rL = blk_sum(vL, sm);
  const float rR = blk_sum(vR, sm);
  if (threadIdx.x == 0) {
    ws[OFS_VOTE + blockIdx.x]         = rL;
    ws[OFS_VOTE + NVBLK + blockIdx.x] = rR;
  }
}

// ---- Kernel 1b: seg CE + mask count, contiguous streaming ----
// Quad space per side: [b(8)][hwq(16384)] = 131072; iter 0 = side L, iter 1 = side R.
__global__ __launch_bounds__(256) void seg_kernel(
    const int* __restrict__ mkL, const float* __restrict__ sgL,
    const int* __restrict__ mkR, const float* __restrict__ sgR,
    float* __restrict__ ws) {
  const int tid = blockIdx.x * 256 + threadIdx.x;   // 0..131071
  float cnt[2], seg[2];

  int4 m4[2]; float4 s0[2], s1[2];
#pragma unroll
  for (int it = 0; it < 2; ++it) {
    const int*   mk = it ? mkR : mkL;
    const float* sg = it ? sgR : sgL;
    const int b   = tid >> 14;
    const int hwq = tid & 16383;
    const size_t moff = ((size_t)b << 16) + ((size_t)hwq << 2);
    const size_t soff = ((size_t)b << 17) + ((size_t)hwq << 2);
    m4[it] = *(const int4*)(mk + moff);
    s0[it] = *(const float4*)(sg + soff);
    s1[it] = *(const float4*)(sg + soff + HWPIX);
  }
  __builtin_amdgcn_sched_barrier(0);
#pragma unroll
  for (int it = 0; it < 2; ++it) {
    cnt[it] = (float)(m4[it].x + m4[it].y + m4[it].z + m4[it].w);
    float s = 0.f;
    s += nll2(s0[it].x, s1[it].x, m4[it].x);
    s += nll2(s0[it].y, s1[it].y, m4[it].y);
    s += nll2(s0[it].z, s1[it].z, m4[it].z);
    s += nll2(s0[it].w, s1[it].w, m4[it].w);
    seg[it] = s;
  }

  __shared__ float sm[256];
  const float c0 = blk_sum(cnt[0], sm);
  const float c1 = blk_sum(cnt[1], sm);
  const float g0 = blk_sum(seg[0], sm);
  const float g1 = blk_sum(seg[1], sm);
  if (threadIdx.x == 0) {
    ws[OFS_CNT + blockIdx.x]         = c0;
    ws[OFS_CNT + NSBLK + blockIdx.x] = c1;
    ws[OFS_SEG + blockIdx.x]         = g0;
    ws[OFS_SEG + NSBLK + blockIdx.x] = g1;
  }
}

// ---- Kernel 2: per-(b,k,side) softmax (kp loss + entropy) and gumbel-argmax
//      categorical sample -> selected y coordinate ----
__global__ __launch_bounds__(256) void hyp_kernel(
    const float* __restrict__ scL, const float* __restrict__ kpL,
    const float* __restrict__ k2L, const float* __restrict__ ofL,
    const float* __restrict__ scR, const float* __restrict__ kpR,
    const float* __restrict__ k2R, const float* __restrict__ ofR,
    const float* __restrict__ aPtr,
    uint32_t kLa, uint32_t kLb, uint32_t kRa, uint32_t kRb,
    float* __restrict__ ws) {
  const int side = blockIdx.y;
  const float* sc = side ? scR : scL;
  const float* kp = side ? kpR : kpL;
  const float* k2 = side ? k2R : k2L;
  const float* of = side ? ofR : ofL;
  const uint32_t K0 = side ? kRa : kLa;
  const uint32_t K1 = side ? kRb : kLb;
  const int bk = blockIdx.x;          // 0..71
  const int b = bk / NK, k = bk % NK;
  const int t = threadIdx.x;
  const float a = aPtr[0];
  const float kx = k2[(b * NK + k) * 2 + 0];
  const float ky = k2[(b * NK + k) * 2 + 1];
  const float2* kp2 = (const float2*)kp;

  float s[4], d[4], gv[4];
#pragma unroll
  for (int j = 0; j < 4; ++j) {
    const int n = t + j * 256;
    const size_t idx = ((size_t)b * NHYP + n) * NK + k;   // row-major flat index of (b,n,k)
    s[j] = a * sc[idx];
    const float2 xy = kp2[idx];
    const float dx = xy.x - kx, dy = xy.y - ky;
    d[j] = sqrtf(dx * dx + dy * dy);
    // JAX partitionable random bits: bits = out0 ^ out1 of threefry(key, (0, flat_idx))
    uint32_t o0, o1;
    tf2x32(K0, K1, 0u, (uint32_t)idx, o0, o1);
    const uint32_t bits = o0 ^ o1;
    float u = __uint_as_float((bits >> 9) | 0x3F800000u) - 1.0f;   // [0,1)
    u = fmaxf(TINYF, u * (1.0f - TINYF) + TINYF);                  // uniform(tiny, 1)
    gv[j] = -logf(-logf(u)) + s[j];                                // gumbel + logits
  }

  __shared__ float sm[256];
  __shared__ int   si[256];

  // block max of logits
  float mx = fmaxf(fmaxf(s[0], s[1]), fmaxf(s[2], s[3]));
  sm[t] = mx; __syncthreads();
  for (int off = 128; off > 0; off >>= 1) {
    if (t < off) sm[t] = fmaxf(sm[t], sm[t + off]);
    __syncthreads();
  }
  mx = sm[0]; __syncthreads();

  float Z = 0.f, Sd = 0.f, Ss = 0.f;
#pragma unroll
  for (int j = 0; j < 4; ++j) {
    const float e = expf(s[j] - mx);
    Z  += e;
    Sd += e * d[j];
    Ss += e * (s[j] - mx);
  }
  Z  = blk_sum(Z, sm);
  Sd = blk_sum(Sd, sm);
  Ss = blk_sum(Ss, sm);

  // argmax of gumbel+logits, first-index tie-break (matches jnp.argmax)
  float bv = gv[0]; int bi = t;
#pragma unroll
  for (int j = 1; j < 4; ++j) {
    const int n = t + j * 256;
    if (gv[j] > bv) { bv = gv[j]; bi = n; }
  }
  sm[t] = bv; si[t] = bi; __syncthreads();
  for (int off = 128; off > 0; off >>= 1) {
    if (t < off) {
      const float v2 = sm[t + off]; const int i2 = si[t + off];
      if (v2 > sm[t] || (v2 == sm[t] && i2 < si[t])) { sm[t] = v2; si[t] = i2; }
    }
    __syncthreads();
  }

  if (t == 0) {
    ws[OFS_KP  + side * NBK + bk] = Sd / Z;
    ws[OFS_ENT + side * NBK + bk] = (logf(Z) - Ss / Z) * INV_LOG2;  // entropy in bits
    const int n = si[0];
    ws[OFS_Y + side * NBK + bk] =
        kp2[((size_t)b * NHYP + n) * NK + k].y + of[b * 2 + 1];
  }
}

// ---- Kernel 3: stage-2 reductions + scalar combine ----
__global__ __launch_bounds__(256) void final_kernel(
    const int* __restrict__ epochPtr, const float* __restrict__ ws,
    float* __restrict__ out) {
  __shared__ float sm[256];
  const int t = threadIdx.x;
  float voteS[2], cntS[2], segS[2], kpS[2], entS[2];
  for (int side = 0; side < 2; ++side) {
    float a;
    a = 0.f; for (int j = t; j < NVBLK; j += 256) a += ws[OFS_VOTE + side * NVBLK + j];
    voteS[side] = blk_sum(a, sm);
    a = 0.f; for (int j = t; j < NSBLK; j += 256) a += ws[OFS_CNT + side * NSBLK + j];
    cntS[side] = blk_sum(a, sm);
    a = 0.f; for (int j = t; j < NSBLK; j += 256) a += ws[OFS_SEG + side * NSBLK + j];
    segS[side] = blk_sum(a, sm);
    a = (t < NBK) ? ws[OFS_KP + side * NBK + t] : 0.f;
    kpS[side] = blk_sum(a, sm);
    a = 0.f;
    if (t < 8) {
      float es = 0.f;
      for (int k = 0; k < NK; ++k) es += ws[OFS_ENT + side * NBK + t * NK + k];
      a = fabsf(es / (float)NK - 6.0f);
    }
    entS[side] = blk_sum(a, sm);
  }
  float e = 0.f;
  if (t < NBK) {
    const float dy = fabsf(ws[OFS_Y + t] - ws[OFS_Y + NBK + t]);
    e = isfinite(dy) ? dy : 0.f;
  }
  const float epiSum = blk_sum(e, sm);

  if (t == 0) {
    const float voteL = (cntS[0] > 0.f) ? voteS[0] / fmaxf(cntS[0], 1.f) / (float)NCH : voteS[0];
    const float voteR = (cntS[1] > 0.f) ? voteS[1] / fmaxf(cntS[1], 1.f) / (float)NCH : voteS[1];
    const float segL = segS[0] / 524288.f;
    const float segR = segS[1] / 524288.f;
    const float kpLm = kpS[0] / (float)NBK, kpRm = kpS[1] / (float)NBK;
    const float entL = entS[0] / 8.f, entR = entS[1] / 8.f;

    const float vote_loss = 0.5f * (voteL + voteR);
    const float seg_loss  = 0.5f * (segL + segR);
    const float kp_loss   = 0.5f * (kpLm + kpRm);
    const float ent_loss  = 0.5f * (entL + entR);
    const float kp_w  = 1.f / (1.f + expf(-0.5f * (20.f - kp_loss)));
    const float vote_w = 1.f - kp_w;
    float vertex;
    if (epochPtr[0] > 49) {
      const float epi = epiSum / (float)NBK;
      vertex = kp_w * (kp_loss + epi) + vote_w * vote_loss;
    } else {
      vertex = kp_w * kp_loss + vote_w * vote_loss;
    }
    out[0] = vertex + ent_loss + seg_loss;
  }
}

extern "C" void kernel_launch(void* const* d_in, const int* in_sizes, int n_in,
                              void* d_out, int out_size, void* d_ws, size_t ws_size,
                              hipStream_t stream) {
  (void)in_sizes; (void)n_in; (void)out_size; (void)ws_size;
  const float* vpL = (const float*)d_in[0];
  const float* vgL = (const float*)d_in[1];
  const int*   mkL = (const int*)  d_in[2];
  const float* sgL = (const float*)d_in[3];
  const float* kpL = (const float*)d_in[4];
  const float* scL = (const float*)d_in[5];
  const float* k2L = (const float*)d_in[6];
  const float* ofL = (const float*)d_in[7];
  const float* vpR = (const float*)d_in[8];
  const float* vgR = (const float*)d_in[9];
  const int*   mkR = (const int*)  d_in[10];
  const float* sgR = (const float*)d_in[11];
  const float* kpR = (const float*)d_in[12];
  const float* scR = (const float*)d_in[13];
  const float* k2R = (const float*)d_in[14];
  const float* ofR = (const float*)d_in[15];
  const float* aP  = (const float*)d_in[16];
  const int*   epP = (const int*)  d_in[17];
  float* ws  = (float*)d_ws;
  float* out = (float*)d_out;

  // jax.random.split(jax.random.key(1234)) — partitionable ("foldlike") split:
  // kL = threefry(key, (0,0)), kR = threefry(key, (0,1)), key = [0, 1234]
  uint32_t kLa, kLb, kRa, kRb;
  tf2x32(0u, 1234u, 0u, 0u, kLa, kLb);
  tf2x32(0u, 1234u, 0u, 1u, kRa, kRb);

  pixel_kernel<<<NVBLK, 256, 0, stream>>>(vpL, vgL, mkL, vpR, vgR, mkR, ws);
  seg_kernel<<<NSBLK, 256, 0, stream>>>(mkL, sgL, mkR, sgR, ws);
  hyp_kernel<<<dim3(NBK, 2), 256, 0, stream>>>(
      scL, kpL, k2L, ofL, scR, kpR, k2R, ofR, aP, kLa, kLb, kRa, kRb, ws);
  final_kernel<<<1, 256, 0, stream>>>(epP, ws, out);
}

// Round 4
// 52.486 us; speedup vs baseline: 1.1367x; 1.1367x over previous
//
#include <hip/hip_runtime.h>
#include <stdint.h>
#include <math.h>

// Problem geometry (fixed by reference)
#define HWPIX 65536         // 256*256
#define NCH   18
#define NHYP  1024
#define NK    9
#define NBK   72            // B*K = 8*9
#define INV_LOG2 1.4426950408889634f
#define TINYF 1.1754943508222875e-38f

// pixel kernel geometry: 2048 blocks = [side(2)][b(8)][half(2)][blk64(64)], 256 thr
#define NVB_SIDE 1024       // vote partials per side
#define NSB_SIDE 512        // seg/cnt partials per side (half==0 blocks)

// ws layout (floats)
#define OFS_VOTE 64                          // [2][NVB_SIDE]
#define OFS_CNT  (OFS_VOTE + 2 * NVB_SIDE)   // [2][NSB_SIDE]
#define OFS_SEG  (OFS_CNT  + 2 * NSB_SIDE)   // [2][NSB_SIDE]
#define OFS_KP   (OFS_SEG  + 2 * NSB_SIDE)   // [2][NBK]
#define OFS_ENT  (OFS_KP   + 2 * NBK)        // [2][NBK]
#define OFS_Y    (OFS_ENT  + 2 * NBK)        // [2][NBK]

// ---- Threefry-2x32, 20 rounds (JAX-compatible) ----
__host__ __device__ inline void tf2x32(uint32_t k0, uint32_t k1,
                                       uint32_t x0, uint32_t x1,
                                       uint32_t& o0, uint32_t& o1) {
  uint32_t ks2 = k0 ^ k1 ^ 0x1BD11BDAu;
  x0 += k0; x1 += k1;
#define TFR(r) { x0 += x1; x1 = (x1 << (r)) | (x1 >> (32 - (r))); x1 ^= x0; }
  TFR(13) TFR(15) TFR(26) TFR(6)   x0 += k1;  x1 += ks2 + 1u;
  TFR(17) TFR(29) TFR(16) TFR(24)  x0 += ks2; x1 += k0 + 2u;
  TFR(13) TFR(15) TFR(26) TFR(6)   x0 += k0;  x1 += k1 + 3u;
  TFR(17) TFR(29) TFR(16) TFR(24)  x0 += k1;  x1 += ks2 + 4u;
  TFR(13) TFR(15) TFR(26) TFR(6)   x0 += ks2; x1 += k0 + 5u;
#undef TFR
  o0 = x0; o1 = x1;
}

__device__ inline float blk_sum(float v, float* sm) {
  int t = threadIdx.x;
  sm[t] = v; __syncthreads();
  for (int off = 128; off > 0; off >>= 1) {
    if (t < off) sm[t] += sm[t + off];
    __syncthreads();
  }
  float r = sm[0]; __syncthreads();
  return r;
}

__device__ inline float sl1(float x, float y, float w) {
  const float dd = fabsf(x - y) * w;
  return (dd < 1.f) ? 0.5f * dd * dd : dd - 0.5f;
}

__device__ inline float nll2(float s0, float s1, int lbl) {
  const float mx = fmaxf(s0, s1);
  const float mn = fminf(s0, s1);
  const float l = mx + logf(1.0f + expf(mn - mx));
  return l - (lbl ? s1 : s0);
}

#define LD4(p) (*(const float4*)(p))

// ---- Kernel 1: masked smooth-L1 vote + (half==0) seg CE + mask count ----
// block -> (side, b, half, blk64); thread -> one pixel-quad, 9 channels.
// Mask read ONCE per thread; channel pairs walked with a depth-2 register
// pipeline so ~4 vertex loads stay in flight per wave.
__global__ __launch_bounds__(256, 8) void pixel_kernel(
    const float* __restrict__ vpL, const float* __restrict__ vgL,
    const int*   __restrict__ mkL, const float* __restrict__ sgL,
    const float* __restrict__ vpR, const float* __restrict__ vgR,
    const int*   __restrict__ mkR, const float* __restrict__ sgR,
    float* __restrict__ ws) {
  const int t     = threadIdx.x;
  const int bid   = blockIdx.x;          // 0..2047
  const int side  = bid >> 10;
  const int v     = bid & 1023;
  const int b     = v >> 7;
  const int half  = (v >> 6) & 1;
  const int blk64 = v & 63;
  const int hwq   = blk64 * 256 + t;     // quad index 0..16383

  const float* vp = side ? vpR : vpL;
  const float* vg = side ? vgR : vgL;
  const int*   mk = side ? mkR : mkL;
  const float* sg = side ? sgR : sgL;

  // mask once
  const int4 m4 = *(const int4*)(mk + ((size_t)b << 16) + ((size_t)hwq << 2));
  const float w0 = (float)m4.x, w1 = (float)m4.y, w2 = (float)m4.z, w3 = (float)m4.w;

  // seg loads issued early (half==0 blocks only) — latency hidden under loop
  float4 s0 = make_float4(0.f, 0.f, 0.f, 0.f), s1 = s0;
  if (half == 0) {
    const size_t soff = ((size_t)b << 17) + ((size_t)hwq << 2);
    s0 = LD4(sg + soff);
    s1 = LD4(sg + soff + HWPIX);
  }

  // channel walk: c = half*9 + j, j = 0..8
  const size_t pbase = ((size_t)(b * NCH + half * 9) << 16) + ((size_t)hwq << 2);
  const float* pp = vp + pbase;
  const float* qq = vg + pbase;

  float4 Pa = LD4(pp);              float4 Qa = LD4(qq);
  float4 Pb = LD4(pp + HWPIX);      float4 Qb = LD4(qq + HWPIX);

  float acc = 0.f;
#pragma unroll
  for (int j = 0; j < 9; ++j) {
    float4 pc, qc;
    if ((j & 1) == 0) {
      pc = Pa; qc = Qa;
      if (j + 2 < 9) { Pa = LD4(pp + (size_t)(j + 2) * HWPIX); Qa = LD4(qq + (size_t)(j + 2) * HWPIX); }
    } else {
      pc = Pb; qc = Qb;
      if (j + 2 < 9) { Pb = LD4(pp + (size_t)(j + 2) * HWPIX); Qb = LD4(qq + (size_t)(j + 2) * HWPIX); }
    }
    acc += sl1(pc.x, qc.x, w0);
    acc += sl1(pc.y, qc.y, w1);
    acc += sl1(pc.z, qc.z, w2);
    acc += sl1(pc.w, qc.w, w3);
  }

  __shared__ float sm[256];
  const float rvote = blk_sum(acc, sm);
  if (t == 0) ws[OFS_VOTE + side * NVB_SIDE + v] = rvote;

  if (half == 0) {
    float seg = 0.f;
    seg += nll2(s0.x, s1.x, m4.x);
    seg += nll2(s0.y, s1.y, m4.y);
    seg += nll2(s0.z, s1.z, m4.z);
    seg += nll2(s0.w, s1.w, m4.w);
    const float cnt = w0 + w1 + w2 + w3;
    const float rcnt = blk_sum(cnt, sm);
    const float rseg = blk_sum(seg, sm);
    if (t == 0) {
      const int s = b * 64 + blk64;
      ws[OFS_CNT + side * NSB_SIDE + s] = rcnt;
      ws[OFS_SEG + side * NSB_SIDE + s] = rseg;
    }
  }
}

// ---- Kernel 2: per-(b,k,side) softmax (kp loss + entropy) and gumbel-argmax
//      categorical sample -> selected y coordinate ----
__global__ __launch_bounds__(256) void hyp_kernel(
    const float* __restrict__ scL, const float* __restrict__ kpL,
    const float* __restrict__ k2L, const float* __restrict__ ofL,
    const float* __restrict__ scR, const float* __restrict__ kpR,
    const float* __restrict__ k2R, const float* __restrict__ ofR,
    const float* __restrict__ aPtr,
    uint32_t kLa, uint32_t kLb, uint32_t kRa, uint32_t kRb,
    float* __restrict__ ws) {
  const int side = blockIdx.y;
  const float* sc = side ? scR : scL;
  const float* kp = side ? kpR : kpL;
  const float* k2 = side ? k2R : k2L;
  const float* of = side ? ofR : ofL;
  const uint32_t K0 = side ? kRa : kLa;
  const uint32_t K1 = side ? kRb : kLb;
  const int bk = blockIdx.x;          // 0..71
  const int b = bk / NK, k = bk % NK;
  const int t = threadIdx.x;
  const float a = aPtr[0];
  const float kx = k2[(b * NK + k) * 2 + 0];
  const float ky = k2[(b * NK + k) * 2 + 1];
  const float2* kp2 = (const float2*)kp;

  float s[4], d[4], gv[4];
#pragma unroll
  for (int j = 0; j < 4; ++j) {
    const int n = t + j * 256;
    const size_t idx = ((size_t)b * NHYP + n) * NK + k;   // row-major flat index of (b,n,k)
    s[j] = a * sc[idx];
    const float2 xy = kp2[idx];
    const float dx = xy.x - kx, dy = xy.y - ky;
    d[j] = sqrtf(dx * dx + dy * dy);
    // JAX partitionable random bits: bits = out0 ^ out1 of threefry(key, (0, flat_idx))
    uint32_t o0, o1;
    tf2x32(K0, K1, 0u, (uint32_t)idx, o0, o1);
    const uint32_t bits = o0 ^ o1;
    float u = __uint_as_float((bits >> 9) | 0x3F800000u) - 1.0f;   // [0,1)
    u = fmaxf(TINYF, u * (1.0f - TINYF) + TINYF);                  // uniform(tiny, 1)
    gv[j] = -logf(-logf(u)) + s[j];                                // gumbel + logits
  }

  __shared__ float sm[256];
  __shared__ int   si[256];

  // block max of logits
  float mx = fmaxf(fmaxf(s[0], s[1]), fmaxf(s[2], s[3]));
  sm[t] = mx; __syncthreads();
  for (int off = 128; off > 0; off >>= 1) {
    if (t < off) sm[t] = fmaxf(sm[t], sm[t + off]);
    __syncthreads();
  }
  mx = sm[0]; __syncthreads();

  float Z = 0.f, Sd = 0.f, Ss = 0.f;
#pragma unroll
  for (int j = 0; j < 4; ++j) {
    const float e = expf(s[j] - mx);
    Z  += e;
    Sd += e * d[j];
    Ss += e * (s[j] - mx);
  }
  Z  = blk_sum(Z, sm);
  Sd = blk_sum(Sd, sm);
  Ss = blk_sum(Ss, sm);

  // argmax of gumbel+logits, first-index tie-break (matches jnp.argmax)
  float bv = gv[0]; int bi = t;
#pragma unroll
  for (int j = 1; j < 4; ++j) {
    const int n = t + j * 256;
    if (gv[j] > bv) { bv = gv[j]; bi = n; }
  }
  sm[t] = bv; si[t] = bi; __syncthreads();
  for (int off = 128; off > 0; off >>= 1) {
    if (t < off) {
      const float v2 = sm[t + off]; const int i2 = si[t + off];
      if (v2 > sm[t] || (v2 == sm[t] && i2 < si[t])) { sm[t] = v2; si[t] = i2; }
    }
    __syncthreads();
  }

  if (t == 0) {
    ws[OFS_KP  + side * NBK + bk] = Sd / Z;
    ws[OFS_ENT + side * NBK + bk] = (logf(Z) - Ss / Z) * INV_LOG2;  // entropy in bits
    const int n = si[0];
    ws[OFS_Y + side * NBK + bk] =
        kp2[((size_t)b * NHYP + n) * NK + k].y + of[b * 2 + 1];
  }
}

// ---- Kernel 3: stage-2 reductions + scalar combine ----
__global__ __launch_bounds__(256) void final_kernel(
    const int* __restrict__ epochPtr, const float* __restrict__ ws,
    float* __restrict__ out) {
  __shared__ float sm[256];
  const int t = threadIdx.x;
  float voteS[2], cntS[2], segS[2], kpS[2], entS[2];
  for (int side = 0; side < 2; ++side) {
    float a;
    a = 0.f; for (int j = t; j < NVB_SIDE; j += 256) a += ws[OFS_VOTE + side * NVB_SIDE + j];
    voteS[side] = blk_sum(a, sm);
    a = 0.f; for (int j = t; j < NSB_SIDE; j += 256) a += ws[OFS_CNT + side * NSB_SIDE + j];
    cntS[side] = blk_sum(a, sm);
    a = 0.f; for (int j = t; j < NSB_SIDE; j += 256) a += ws[OFS_SEG + side * NSB_SIDE + j];
    segS[side] = blk_sum(a, sm);
    a = (t < NBK) ? ws[OFS_KP + side * NBK + t] : 0.f;
    kpS[side] = blk_sum(a, sm);
    a = 0.f;
    if (t < 8) {
      float es = 0.f;
      for (int k = 0; k < NK; ++k) es += ws[OFS_ENT + side * NBK + t * NK + k];
      a = fabsf(es / (float)NK - 6.0f);
    }
    entS[side] = blk_sum(a, sm);
  }
  float e = 0.f;
  if (t < NBK) {
    const float dy = fabsf(ws[OFS_Y + t] - ws[OFS_Y + NBK + t]);
    e = isfinite(dy) ? dy : 0.f;
  }
  const float epiSum = blk_sum(e, sm);

  if (t == 0) {
    const float voteL = (cntS[0] > 0.f) ? voteS[0] / fmaxf(cntS[0], 1.f) / (float)NCH : voteS[0];
    const float voteR = (cntS[1] > 0.f) ? voteS[1] / fmaxf(cntS[1], 1.f) / (float)NCH : voteS[1];
    const float segL = segS[0] / 524288.f;
    const float segR = segS[1] / 524288.f;
    const float kpLm = kpS[0] / (float)NBK, kpRm = kpS[1] / (float)NBK;
    const float entL = entS[0] / 8.f, entR = entS[1] / 8.f;

    const float vote_loss = 0.5f * (voteL + voteR);
    const float seg_loss  = 0.5f * (segL + segR);
    const float kp_loss   = 0.5f * (kpLm + kpRm);
    const float ent_loss  = 0.5f * (entL + entR);
    const float kp_w  = 1.f / (1.f + expf(-0.5f * (20.f - kp_loss)));
    const float vote_w = 1.f - kp_w;
    float vertex;
    if (epochPtr[0] > 49) {
      const float epi = epiSum / (float)NBK;
      vertex = kp_w * (kp_loss + epi) + vote_w * vote_loss;
    } else {
      vertex = kp_w * kp_loss + vote_w * vote_loss;
    }
    out[0] = vertex + ent_loss + seg_loss;
  }
}

extern "C" void kernel_launch(void* const* d_in, const int* in_sizes, int n_in,
                              void* d_out, int out_size, void* d_ws, size_t ws_size,
                              hipStream_t stream) {
  (void)in_sizes; (void)n_in; (void)out_size; (void)ws_size;
  const float* vpL = (const float*)d_in[0];
  const float* vgL = (const float*)d_in[1];
  const int*   mkL = (const int*)  d_in[2];
  const float* sgL = (const float*)d_in[3];
  const float* kpL = (const float*)d_in[4];
  const float* scL = (const float*)d_in[5];
  const float* k2L = (const float*)d_in[6];
  const float* ofL = (const float*)d_in[7];
  const float* vpR = (const float*)d_in[8];
  const float* vgR = (const float*)d_in[9];
  const int*   mkR = (const int*)  d_in[10];
  const float* sgR = (const float*)d_in[11];
  const float* kpR = (const float*)d_in[12];
  const float* scR = (const float*)d_in[13];
  const float* k2R = (const float*)d_in[14];
  const float* ofR = (const float*)d_in[15];
  const float* aP  = (const float*)d_in[16];
  const int*   epP = (const int*)  d_in[17];
  float* ws  = (float*)d_ws;
  float* out = (float*)d_out;

  // jax.random.split(jax.random.key(1234)) — partitionable ("foldlike") split:
  // kL = threefry(key, (0,0)), kR = threefry(key, (0,1)), key = [0, 1234]
  uint32_t kLa, kLb, kRa, kRb;
  tf2x32(0u, 1234u, 0u, 0u, kLa, kLb);
  tf2x32(0u, 1234u, 0u, 1u, kRa, kRb);

  pixel_kernel<<<2048, 256, 0, stream>>>(vpL, vgL, mkL, sgL, vpR, vgR, mkR, sgR, ws);
  hyp_kernel<<<dim3(NBK, 2), 256, 0, stream>>>(
      scL, kpL, k2L, ofL, scR, kpR, k2R, ofR, aP, kLa, kLb, kRa, kRb, ws);
  final_kernel<<<1, 256, 0, stream>>>(epP, ws, out);
}

// Round 6
// 47.389 us; speedup vs baseline: 1.2590x; 1.1076x over previous
//
#include <hip/hip_runtime.h>
#include <stdint.h>
#include <math.h>

// Problem geometry (fixed by reference)
#define HWPIX 65536         // 256*256
#define NCH   18
#define NHYP  1024
#define NK    9
#define NBK   72            // B*K = 8*9
#define INV_LOG2 1.4426950408889634f
#define TINYF 1.1754943508222875e-38f

// pixel part: 2048 blocks = [side(2)][b(8)][half(2)][blk64(64)], 256 thr
// hyp part:   144 blocks appended (bid 2048..2191)
#define NPIXB 2048
#define NVB_SIDE 1024       // vote partials per side
#define NSB_SIDE 512        // seg/cnt partials per side (half==0 blocks)

// ws layout (floats)
#define OFS_VOTE 64                          // [2][NVB_SIDE]
#define OFS_CNT  (OFS_VOTE + 2 * NVB_SIDE)   // [2][NSB_SIDE]
#define OFS_SEG  (OFS_CNT  + 2 * NSB_SIDE)   // [2][NSB_SIDE]
#define OFS_KP   (OFS_SEG  + 2 * NSB_SIDE)   // [2][NBK]
#define OFS_ENT  (OFS_KP   + 2 * NBK)        // [2][NBK]
#define OFS_Y    (OFS_ENT  + 2 * NBK)        // [2][NBK]

// native clang vector types (accepted by __builtin_nontemporal_load)
typedef float fx4 __attribute__((ext_vector_type(4)));
typedef int   ix4 __attribute__((ext_vector_type(4)));

// ---- Threefry-2x32, 20 rounds (JAX-compatible) ----
__host__ __device__ inline void tf2x32(uint32_t k0, uint32_t k1,
                                       uint32_t x0, uint32_t x1,
                                       uint32_t& o0, uint32_t& o1) {
  uint32_t ks2 = k0 ^ k1 ^ 0x1BD11BDAu;
  x0 += k0; x1 += k1;
#define TFR(r) { x0 += x1; x1 = (x1 << (r)) | (x1 >> (32 - (r))); x1 ^= x0; }
  TFR(13) TFR(15) TFR(26) TFR(6)   x0 += k1;  x1 += ks2 + 1u;
  TFR(17) TFR(29) TFR(16) TFR(24)  x0 += ks2; x1 += k0 + 2u;
  TFR(13) TFR(15) TFR(26) TFR(6)   x0 += k0;  x1 += k1 + 3u;
  TFR(17) TFR(29) TFR(16) TFR(24)  x0 += k1;  x1 += ks2 + 4u;
  TFR(13) TFR(15) TFR(26) TFR(6)   x0 += ks2; x1 += k0 + 5u;
#undef TFR
  o0 = x0; o1 = x1;
}

__device__ inline float blk_sum(float v, float* sm) {
  int t = threadIdx.x;
  sm[t] = v; __syncthreads();
  for (int off = 128; off > 0; off >>= 1) {
    if (t < off) sm[t] += sm[t + off];
    __syncthreads();
  }
  float r = sm[0]; __syncthreads();
  return r;
}

__device__ inline float sl1(float x, float y, float w) {
  const float dd = fabsf(x - y) * w;
  return (dd < 1.f) ? 0.5f * dd * dd : dd - 0.5f;
}

__device__ inline float nll2(float s0, float s1, int lbl) {
  const float mx = fmaxf(s0, s1);
  const float mn = fminf(s0, s1);
  const float l = mx + logf(1.0f + expf(mn - mx));
  return l - (lbl ? s1 : s0);
}

// non-temporal (L2-bypass) vector loads for streamed data
__device__ inline fx4 ldnt4(const float* p) {
  return __builtin_nontemporal_load((const fx4*)p);
}
__device__ inline ix4 ldnt4i(const int* p) {
  return __builtin_nontemporal_load((const ix4*)p);
}

// ---- Fused kernel: pixel blocks (0..2047) + hyp blocks (2048..2191) ----
__global__ __launch_bounds__(256, 8) void fused_kernel(
    const float* __restrict__ vpL, const float* __restrict__ vgL,
    const int*   __restrict__ mkL, const float* __restrict__ sgL,
    const float* __restrict__ vpR, const float* __restrict__ vgR,
    const int*   __restrict__ mkR, const float* __restrict__ sgR,
    const float* __restrict__ scL, const float* __restrict__ kpL,
    const float* __restrict__ k2L, const float* __restrict__ ofL,
    const float* __restrict__ scR, const float* __restrict__ kpR,
    const float* __restrict__ k2R, const float* __restrict__ ofR,
    const float* __restrict__ aPtr,
    uint32_t kLa, uint32_t kLb, uint32_t kRa, uint32_t kRb,
    float* __restrict__ ws) {
  const int t   = threadIdx.x;
  const int bid = blockIdx.x;

  if (bid < NPIXB) {
    // ================= pixel path =================
    const int side  = bid >> 10;
    const int v     = bid & 1023;
    const int b     = v >> 7;
    const int half  = (v >> 6) & 1;
    const int blk64 = v & 63;
    const int hwq   = blk64 * 256 + t;     // quad index 0..16383

    const float* vp = side ? vpR : vpL;
    const float* vg = side ? vgR : vgL;
    const int*   mk = side ? mkR : mkL;
    const float* sg = side ? sgR : sgL;

    // mask once
    const ix4 m4 = ldnt4i(mk + ((size_t)b << 16) + ((size_t)hwq << 2));
    const float w0 = (float)m4.x, w1 = (float)m4.y, w2 = (float)m4.z, w3 = (float)m4.w;

    // seg loads issued early (half==0 blocks only)
    fx4 s0 = (fx4)0.f, s1 = (fx4)0.f;
    if (half == 0) {
      const size_t soff = ((size_t)b << 17) + ((size_t)hwq << 2);
      s0 = ldnt4(sg + soff);
      s1 = ldnt4(sg + soff + HWPIX);
    }

    // channel walk: c = half*9 + j, j = 0..8
    const size_t pbase = ((size_t)(b * NCH + half * 9) << 16) + ((size_t)hwq << 2);
    const float* pp = vp + pbase;
    const float* qq = vg + pbase;

    fx4 Pa = ldnt4(pp);              fx4 Qa = ldnt4(qq);
    fx4 Pb = ldnt4(pp + HWPIX);      fx4 Qb = ldnt4(qq + HWPIX);

    float acc = 0.f;
#pragma unroll
    for (int j = 0; j < 9; ++j) {
      fx4 pc, qc;
      if ((j & 1) == 0) {
        pc = Pa; qc = Qa;
        if (j + 2 < 9) { Pa = ldnt4(pp + (size_t)(j + 2) * HWPIX); Qa = ldnt4(qq + (size_t)(j + 2) * HWPIX); }
      } else {
        pc = Pb; qc = Qb;
        if (j + 2 < 9) { Pb = ldnt4(pp + (size_t)(j + 2) * HWPIX); Qb = ldnt4(qq + (size_t)(j + 2) * HWPIX); }
      }
      acc += sl1(pc.x, qc.x, w0);
      acc += sl1(pc.y, qc.y, w1);
      acc += sl1(pc.z, qc.z, w2);
      acc += sl1(pc.w, qc.w, w3);
    }

    __shared__ float smp[256];
    const float rvote = blk_sum(acc, smp);
    if (t == 0) ws[OFS_VOTE + side * NVB_SIDE + v] = rvote;

    if (half == 0) {
      float seg = 0.f;
      seg += nll2(s0.x, s1.x, m4.x);
      seg += nll2(s0.y, s1.y, m4.y);
      seg += nll2(s0.z, s1.z, m4.z);
      seg += nll2(s0.w, s1.w, m4.w);
      const float cnt = w0 + w1 + w2 + w3;
      const float rcnt = blk_sum(cnt, smp);
      const float rseg = blk_sum(seg, smp);
      if (t == 0) {
        const int s = b * 64 + blk64;
        ws[OFS_CNT + side * NSB_SIDE + s] = rcnt;
        ws[OFS_SEG + side * NSB_SIDE + s] = rseg;
      }
    }
    return;
  }

  // ================= hyp path =================
  const int hid  = bid - NPIXB;       // 0..143
  const int side = hid / NBK;
  const int bk   = hid % NBK;         // 0..71
  const float* sc = side ? scR : scL;
  const float* kp = side ? kpR : kpL;
  const float* k2 = side ? k2R : k2L;
  const float* of = side ? ofR : ofL;
  const uint32_t K0 = side ? kRa : kLa;
  const uint32_t K1 = side ? kRb : kLb;
  const int b = bk / NK, k = bk % NK;
  const float a = aPtr[0];
  const float kx = k2[(b * NK + k) * 2 + 0];
  const float ky = k2[(b * NK + k) * 2 + 1];
  const float2* kp2 = (const float2*)kp;

  float s[4], d[4], gv[4];
#pragma unroll
  for (int j = 0; j < 4; ++j) {
    const int n = t + j * 256;
    const size_t idx = ((size_t)b * NHYP + n) * NK + k;   // flat index of (b,n,k)
    s[j] = a * sc[idx];
    const float2 xy = kp2[idx];
    const float dx = xy.x - kx, dy = xy.y - ky;
    d[j] = sqrtf(dx * dx + dy * dy);
    // JAX partitionable random bits: bits = out0 ^ out1 of threefry(key, (0, flat_idx))
    uint32_t o0, o1;
    tf2x32(K0, K1, 0u, (uint32_t)idx, o0, o1);
    const uint32_t bits = o0 ^ o1;
    float u = __uint_as_float((bits >> 9) | 0x3F800000u) - 1.0f;   // [0,1)
    u = fmaxf(TINYF, u * (1.0f - TINYF) + TINYF);                  // uniform(tiny, 1)
    gv[j] = -logf(-logf(u)) + s[j];                                // gumbel + logits
  }

  __shared__ float sm[256];
  __shared__ int   si[256];

  // block max of logits
  float mx = fmaxf(fmaxf(s[0], s[1]), fmaxf(s[2], s[3]));
  sm[t] = mx; __syncthreads();
  for (int off = 128; off > 0; off >>= 1) {
    if (t < off) sm[t] = fmaxf(sm[t], sm[t + off]);
    __syncthreads();
  }
  mx = sm[0]; __syncthreads();

  float Z = 0.f, Sd = 0.f, Ss = 0.f;
#pragma unroll
  for (int j = 0; j < 4; ++j) {
    const float e = expf(s[j] - mx);
    Z  += e;
    Sd += e * d[j];
    Ss += e * (s[j] - mx);
  }
  Z  = blk_sum(Z, sm);
  Sd = blk_sum(Sd, sm);
  Ss = blk_sum(Ss, sm);

  // argmax of gumbel+logits, first-index tie-break (matches jnp.argmax)
  float bv = gv[0]; int bi = t;
#pragma unroll
  for (int j = 1; j < 4; ++j) {
    const int n = t + j * 256;
    if (gv[j] > bv) { bv = gv[j]; bi = n; }
  }
  sm[t] = bv; si[t] = bi; __syncthreads();
  for (int off = 128; off > 0; off >>= 1) {
    if (t < off) {
      const float v2 = sm[t + off]; const int i2 = si[t + off];
      if (v2 > sm[t] || (v2 == sm[t] && i2 < si[t])) { sm[t] = v2; si[t] = i2; }
    }
    __syncthreads();
  }

  if (t == 0) {
    ws[OFS_KP  + side * NBK + bk] = Sd / Z;
    ws[OFS_ENT + side * NBK + bk] = (logf(Z) - Ss / Z) * INV_LOG2;  // entropy in bits
    const int n = si[0];
    ws[OFS_Y + side * NBK + bk] =
        kp2[((size_t)b * NHYP + n) * NK + k].y + of[b * 2 + 1];
  }
}

// ---- Kernel 2: stage-2 reductions + scalar combine ----
__global__ __launch_bounds__(256) void final_kernel(
    const int* __restrict__ epochPtr, const float* __restrict__ ws,
    float* __restrict__ out) {
  __shared__ float sm[256];
  const int t = threadIdx.x;
  float voteS[2], cntS[2], segS[2], kpS[2], entS[2];
  for (int side = 0; side < 2; ++side) {
    float a;
    a = 0.f; for (int j = t; j < NVB_SIDE; j += 256) a += ws[OFS_VOTE + side * NVB_SIDE + j];
    voteS[side] = blk_sum(a, sm);
    a = 0.f; for (int j = t; j < NSB_SIDE; j += 256) a += ws[OFS_CNT + side * NSB_SIDE + j];
    cntS[side] = blk_sum(a, sm);
    a = 0.f; for (int j = t; j < NSB_SIDE; j += 256) a += ws[OFS_SEG + side * NSB_SIDE + j];
    segS[side] = blk_sum(a, sm);
    a = (t < NBK) ? ws[OFS_KP + side * NBK + t] : 0.f;
    kpS[side] = blk_sum(a, sm);
    a = 0.f;
    if (t < 8) {
      float es = 0.f;
      for (int k = 0; k < NK; ++k) es += ws[OFS_ENT + side * NBK + t * NK + k];
      a = fabsf(es / (float)NK - 6.0f);
    }
    entS[side] = blk_sum(a, sm);
  }
  float e = 0.f;
  if (t < NBK) {
    const float dy = fabsf(ws[OFS_Y + t] - ws[OFS_Y + NBK + t]);
    e = isfinite(dy) ? dy : 0.f;
  }
  const float epiSum = blk_sum(e, sm);

  if (t == 0) {
    const float voteL = (cntS[0] > 0.f) ? voteS[0] / fmaxf(cntS[0], 1.f) / (float)NCH : voteS[0];
    const float voteR = (cntS[1] > 0.f) ? voteS[1] / fmaxf(cntS[1], 1.f) / (float)NCH : voteS[1];
    const float segL = segS[0] / 524288.f;
    const float segR = segS[1] / 524288.f;
    const float kpLm = kpS[0] / (float)NBK, kpRm = kpS[1] / (float)NBK;
    const float entL = entS[0] / 8.f, entR = entS[1] / 8.f;

    const float vote_loss = 0.5f * (voteL + voteR);
    const float seg_loss  = 0.5f * (segL + segR);
    const float kp_loss   = 0.5f * (kpLm + kpRm);
    const float ent_loss  = 0.5f * (entL + entR);
    const float kp_w  = 1.f / (1.f + expf(-0.5f * (20.f - kp_loss)));
    const float vote_w = 1.f - kp_w;
    float vertex;
    if (epochPtr[0] > 49) {
      const float epi = epiSum / (float)NBK;
      vertex = kp_w * (kp_loss + epi) + vote_w * vote_loss;
    } else {
      vertex = kp_w * kp_loss + vote_w * vote_loss;
    }
    out[0] = vertex + ent_loss + seg_loss;
  }
}

extern "C" void kernel_launch(void* const* d_in, const int* in_sizes, int n_in,
                              void* d_out, int out_size, void* d_ws, size_t ws_size,
                              hipStream_t stream) {
  (void)in_sizes; (void)n_in; (void)out_size; (void)ws_size;
  const float* vpL = (const float*)d_in[0];
  const float* vgL = (const float*)d_in[1];
  const int*   mkL = (const int*)  d_in[2];
  const float* sgL = (const float*)d_in[3];
  const float* kpL = (const float*)d_in[4];
  const float* scL = (const float*)d_in[5];
  const float* k2L = (const float*)d_in[6];
  const float* ofL = (const float*)d_in[7];
  const float* vpR = (const float*)d_in[8];
  const float* vgR = (const float*)d_in[9];
  const int*   mkR = (const int*)  d_in[10];
  const float* sgR = (const float*)d_in[11];
  const float* kpR = (const float*)d_in[12];
  const float* scR = (const float*)d_in[13];
  const float* k2R = (const float*)d_in[14];
  const float* ofR = (const float*)d_in[15];
  const float* aP  = (const float*)d_in[16];
  const int*   epP = (const int*)  d_in[17];
  float* ws  = (float*)d_ws;
  float* out = (float*)d_out;

  // jax.random.split(jax.random.key(1234)) — partitionable ("foldlike") split:
  // kL = threefry(key, (0,0)), kR = threefry(key, (0,1)), key = [0, 1234]
  uint32_t kLa, kLb, kRa, kRb;
  tf2x32(0u, 1234u, 0u, 0u, kLa, kLb);
  tf2x32(0u, 1234u, 0u, 1u, kRa, kRb);

  fused_kernel<<<NPIXB + 2 * NBK, 256, 0, stream>>>(
      vpL, vgL, mkL, sgL, vpR, vgR, mkR, sgR,
      scL, kpL, k2L, ofL, scR, kpR, k2R, ofR,
      aP, kLa, kLb, kRa, kRb, ws);
  final_kernel<<<1, 256, 0, stream>>>(epP, ws, out);
}